// Round 4
// baseline (335.653 us; speedup 1.0000x reference)
//
#include <hip/hip_runtime.h>
#include <stdint.h>

#define T_TOK 8192
#define HD 1024
#define NE 16
#define NET 17
#define FD 512
#define CAP 8448            // max tokens/expert 8192 + 255 pad (256-row blocks)
#define MAXWG 448           // 112 row-blocks x 4 col-blocks
#define CPX 56              // MAXWG / 8 XCDs

typedef unsigned int uint;
typedef unsigned short ushort;
typedef __attribute__((ext_vector_type(8))) __bf16 bf16x8;
typedef __attribute__((ext_vector_type(4))) float f32x4;

// ws layout (bytes)
#define OFF_XBF   0ull            // 16 MB   (dead after k_up -> ybuf)
#define OFF_WUPT  16777216ull     // 35.65MB (dead after k_up -> ybuf)
#define OFF_WDT   52428800ull     // 17.83MB
#define OFF_ACT   70254592ull     // 24576 x 1024 B = 25.17MB (compact rows)
#define OFF_EIDX  95420416ull     // inv_a (e0,p0) per token
#define OFF_EW    95485952ull     // inv_b (e1,p1) per token
#define OFF_TOK   95551488ull     // 17*CAP ints
#define OFF_WGT   96125952ull
#define OFF_META  96700416ull
#define WS_NEEDED (OFF_META + 4096ull)
// ybuf: compact 24576 rows x 2048 B = 50,331,648 < OFF_WDT. act also compact:
// every row in [0,24576) maps to exactly one valid (expert,slot) and is written.

// meta: [0..16]=cnt (16=shared=8192), [17]=nRB, [32..144)=rbE, [160..272)=rbLoc,
//       [288..400)=rbRow (compact base), [416..433)=ybase per expert

__device__ __forceinline__ ushort f2bf(float f) {
    uint u = __float_as_uint(f);
    u += 0x7FFFu + ((u >> 16) & 1u);
    return (ushort)(u >> 16);
}
__device__ __forceinline__ float bf2f(ushort u) {
    return __uint_as_float(((uint)u) << 16);
}
__device__ __forceinline__ void gload16(const void* g, void* l) {
    __builtin_amdgcn_global_load_lds(
        (const __attribute__((address_space(1))) void*)g,
        (__attribute__((address_space(3))) void*)l, 16, 0, 0);
}

// ---------------- fused prep: router(+assign+convert) | transpose W_up | transpose W_dn ----------------
__global__ __launch_bounds__(256) void k_prep(const float* __restrict__ x,
                                              const float* __restrict__ Wr,
                                              const float* __restrict__ Wup,
                                              const float* __restrict__ Wsup,
                                              const float* __restrict__ Wdn,
                                              const float* __restrict__ Wsdn,
                                              float* __restrict__ probs,
                                              int2* __restrict__ inva,
                                              int2* __restrict__ invb,
                                              ushort* __restrict__ xb,
                                              ushort* __restrict__ wupT,
                                              ushort* __restrict__ wdT,
                                              int* __restrict__ tok,
                                              float* __restrict__ wgt,
                                              int* __restrict__ meta) {
    __shared__ __align__(16) char pshm[5248];
    int bid = blockIdx.x, tid = threadIdx.x;
    if (bid < T_TOK) {
        // ---- router + bf16 convert + bucket-assign for token t ----
        float* xs   = (float*)pshm;            // 1024
        float* part = (float*)(pshm + 4096);   // 256
        float* pl   = (float*)(pshm + 5120);   // 16
        int t = bid;
        float4 xv = *(const float4*)(x + (size_t)t * HD + tid * 4);
        *(float4*)(xs + tid * 4) = xv;
        ushort4 c4;
        c4.x = f2bf(xv.x); c4.y = f2bf(xv.y); c4.z = f2bf(xv.z); c4.w = f2bf(xv.w);
        *(ushort4*)(xb + (size_t)t * HD + tid * 4) = c4;
        __syncthreads();
        int e = tid & 15, g = tid >> 4;
        float s = 0.f;
#pragma unroll 8
        for (int h = g * 64; h < g * 64 + 64; ++h) s += xs[h] * Wr[h * NE + e];
        part[tid] = s;
        __syncthreads();
        if (tid < NE) {
            float l = 0.f;
#pragma unroll
            for (int gg = 0; gg < 16; ++gg) l += part[gg * 16 + tid];
            pl[tid] = l;
        }
        __syncthreads();
        if (tid == 0) {
            float mx = pl[0];
#pragma unroll
            for (int i = 1; i < NE; ++i) mx = fmaxf(mx, pl[i]);
            float p[NE]; float sum = 0.f;
#pragma unroll
            for (int i = 0; i < NE; ++i) { p[i] = __expf(pl[i] - mx); sum += p[i]; }
            float inv = 1.f / sum;
            float m1 = -1.f; int i1 = 0;
#pragma unroll
            for (int i = 0; i < NE; ++i) {
                p[i] *= inv;
                probs[(size_t)t * NE + i] = p[i];
                if (p[i] > m1) { m1 = p[i]; i1 = i; }
            }
            float m2 = -1.f; int i2 = 0;
#pragma unroll
            for (int i = 0; i < NE; ++i) if (i != i1 && p[i] > m2) { m2 = p[i]; i2 = i; }
            float inv2 = 1.f / (m1 + m2 + 1e-9f);
            int p0 = atomicAdd(&meta[i1], 1);
            tok[i1 * CAP + p0] = t; wgt[i1 * CAP + p0] = m1 * inv2;
            int p1 = atomicAdd(&meta[i2], 1);
            tok[i2 * CAP + p1] = t; wgt[i2 * CAP + p1] = m2 * inv2;
            tok[16 * CAP + t] = t; wgt[16 * CAP + t] = 1.f;
            inva[t] = make_int2(i1, p0);
            invb[t] = make_int2(i2, p1);
        }
    } else if (bid < T_TOK + NET * 1024) {
        // ---- W_up [E][H][2F] fp32 -> wupT [17][2F][H] bf16 ----
        float (*tile)[33] = (float(*)[33])pshm;
        int b2 = bid - T_TOK;
        int e = b2 >> 10, rem = b2 & 1023;
        int n0 = (rem & 31) * 32, h0 = (rem >> 5) * 32;
        const float* src = (e < 16) ? (Wup + (size_t)e * HD * (2 * FD)) : Wsup;
        int tx = tid & 31, ty = tid >> 5;
#pragma unroll
        for (int i = 0; i < 4; i++) {
            int r = ty + i * 8;
            tile[r][tx] = src[(size_t)(h0 + r) * (2 * FD) + n0 + tx];
        }
        __syncthreads();
#pragma unroll
        for (int i = 0; i < 4; i++) {
            int r = ty + i * 8;
            wupT[(size_t)e * 1024 * 1024 + (size_t)(n0 + r) * 1024 + h0 + tx] = f2bf(tile[tx][r]);
        }
    } else {
        // ---- W_down [E][F][H] fp32 -> wdT [17][H][F] bf16 ----
        float (*tile)[33] = (float(*)[33])pshm;
        int b3 = bid - T_TOK - NET * 1024;
        int e = b3 >> 9, rem = b3 & 511;
        int h0 = (rem & 31) * 32, f0 = (rem >> 5) * 32;
        const float* src = (e < 16) ? (Wdn + (size_t)e * FD * HD) : Wsdn;
        int tx = tid & 31, ty = tid >> 5;
#pragma unroll
        for (int i = 0; i < 4; i++) {
            int r = ty + i * 8;
            tile[r][tx] = src[(size_t)(f0 + r) * HD + h0 + tx];
        }
        __syncthreads();
#pragma unroll
        for (int i = 0; i < 4; i++) {
            int r = ty + i * 8;
            wdT[(size_t)e * 1024 * 512 + (size_t)(h0 + r) * 512 + f0 + tx] = f2bf(tile[tx][r]);
        }
    }
}

// ---------------- finalize: build 256-row blocks, zero pad slots ----------------
__global__ void k_finalize(int* __restrict__ meta, int* __restrict__ tok,
                           float* __restrict__ wgt) {
    __shared__ int sN[NET], sPad[NET];
    int tid = threadIdx.x;
    if (tid == 0) {
        meta[16] = T_TOK;   // shared-expert count
        int idx = 0, yoff = 0;
        for (int e = 0; e < NET; e++) {
            int n = meta[e];
            int padded = (n + 255) & ~255;
            sN[e] = n; sPad[e] = padded;
            meta[416 + e] = yoff;
            for (int i = 0; i < padded; i += 256) {
                meta[32 + idx] = e; meta[160 + idx] = i; meta[288 + idx] = yoff + i; idx++;
            }
            yoff += n;
        }
        meta[17] = idx;
    }
    __syncthreads();
    for (int e = 0; e < NET; e++)
        for (int i = sN[e] + tid; i < sPad[e]; i += 256) {
            tok[e * CAP + i] = 0; wgt[e * CAP + i] = 0.f;
        }
}

// ---------------- grouped up-GEMM + SiLU ----------------
// BM=256, cols 128 gate + 128 up per block, BK=64, 512 thr (8 waves 4Mx2N),
// double-buffered LDS (2 x {A 32K | Bg 16K | Bu 16K}), depth-1 prefetch.
__global__ __launch_bounds__(512, 2) void k_up(const ushort* __restrict__ xb,
                                               const ushort* __restrict__ wupT,
                                               ushort* __restrict__ act,
                                               const int* __restrict__ tok,
                                               const int* __restrict__ meta) {
    __shared__ __align__(16) char smem[131072];
    int bid = blockIdx.x;
    int s = (bid & 7) * CPX + (bid >> 3);     // XCD swizzle: 4 cb of one rb per XCD
    int rb = s >> 2, cb = s & 3;
    if (rb >= meta[17]) return;
    int e = meta[32 + rb], rloc = meta[160 + rb], abrow = meta[288 + rb];
    int ne = meta[e];
    int tid = threadIdx.x, lane = tid & 63, wave = tid >> 6;

    int srow = tid >> 3;                       // 0..63 (row within 64-row issue)
    int col16 = (tid & 7) << 4;
    int swz = col16 ^ ((srow & 7) << 4);
    const int listBase = e * CAP + rloc;
    int tokr[4];
#pragma unroll
    for (int i = 0; i < 4; i++) tokr[i] = tok[listBase + i * 64 + srow];
    const char* xbase = (const char*)xb;
    const char* wb = (const char*)wupT + (size_t)e * 2097152;
    int ldsl = wave * 1024;                    // wave-uniform LDS slot within each 8KB issue

    int wr = wave >> 1, wc = wave & 1;
    int lr = lane & 15, lk = lane >> 4;
    int aOff = (wr * 64 + lr) * 128;
    int bOff = (wc * 64 + lr) * 128;
    int kp0 = (lk * 16) ^ ((lr & 7) << 4);
    int kp1 = (64 + lk * 16) ^ ((lr & 7) << 4);

    f32x4 accg[4][4], accu[4][4];
#pragma unroll
    for (int m = 0; m < 4; m++)
#pragma unroll
        for (int n = 0; n < 4; n++) {
            accg[m][n] = (f32x4){0.f, 0.f, 0.f, 0.f};
            accu[m][n] = (f32x4){0.f, 0.f, 0.f, 0.f};
        }

#define STAGE_UP(KT, D)                                                                   \
    {                                                                                     \
        char* base = smem + (D) * 65536;                                                  \
        int kB = (KT) * 128;                                                              \
        _Pragma("unroll")                                                                 \
        for (int i = 0; i < 4; i++)                                                       \
            gload16(xbase + (size_t)tokr[i] * 2048 + kB + swz, base + i * 8192 + ldsl);   \
        _Pragma("unroll")                                                                 \
        for (int i = 0; i < 2; i++)                                                       \
            gload16(wb + (size_t)(cb * 128 + i * 64 + srow) * 2048 + kB + swz,            \
                    base + 32768 + i * 8192 + ldsl);                                      \
        _Pragma("unroll")                                                                 \
        for (int i = 0; i < 2; i++)                                                       \
            gload16(wb + (size_t)(512 + cb * 128 + i * 64 + srow) * 2048 + kB + swz,      \
                    base + 49152 + i * 8192 + ldsl);                                      \
    }

    STAGE_UP(0, 0);
    asm volatile("s_waitcnt vmcnt(0)" ::: "memory");
    __syncthreads();
    int cur = 0;
#pragma unroll 1
    for (int kt = 0; kt < 16; ++kt) {
        if (kt < 15) STAGE_UP(kt + 1, cur ^ 1);
        const char* A  = smem + cur * 65536;
        const char* Bg = A + 32768;
        const char* Bu = A + 49152;
#pragma unroll
        for (int kk = 0; kk < 2; kk++) {
            int kp = kk ? kp1 : kp0;
            bf16x8 a[4], bg[4], bu[4];
#pragma unroll
            for (int m = 0; m < 4; m++) a[m] = *(const bf16x8*)(A + aOff + m * 2048 + kp);
#pragma unroll
            for (int n = 0; n < 4; n++) bg[n] = *(const bf16x8*)(Bg + bOff + n * 2048 + kp);
#pragma unroll
            for (int n = 0; n < 4; n++) bu[n] = *(const bf16x8*)(Bu + bOff + n * 2048 + kp);
#pragma unroll
            for (int m = 0; m < 4; m++)
#pragma unroll
                for (int n = 0; n < 4; n++) {
                    accg[m][n] = __builtin_amdgcn_mfma_f32_16x16x32_bf16(a[m], bg[n], accg[m][n], 0, 0, 0);
                    accu[m][n] = __builtin_amdgcn_mfma_f32_16x16x32_bf16(a[m], bu[n], accu[m][n], 0, 0, 0);
                }
        }
        asm volatile("s_waitcnt vmcnt(0)" ::: "memory");
        __syncthreads();
        cur ^= 1;
    }
    // SiLU(gate)*up -> bf16, stage in LDS [256][128]
    ushort* actl = (ushort*)smem;
#pragma unroll
    for (int m = 0; m < 4; m++)
#pragma unroll
        for (int n = 0; n < 4; n++)
#pragma unroll
            for (int j = 0; j < 4; j++) {
                float gv = accg[m][n][j];
                float uv = accu[m][n][j];
                float av = (gv / (1.f + __expf(-gv))) * uv;
                int row = wr * 64 + m * 16 + lk * 4 + j;
                int col = wc * 64 + n * 16 + lr;
                actl[row * 128 + col] = f2bf(av);
            }
    __syncthreads();
#pragma unroll
    for (int p = 0; p < 8; p++) {
        int c = p * 512 + tid;
        int row = c >> 4, off = (c & 15) << 4;
        if (rloc + row < ne)
            *(uint4*)((char*)act + (size_t)(abrow + row) * 1024 + cb * 256 + off) =
                *(const uint4*)((const char*)actl + row * 256 + off);
    }
#undef STAGE_UP
}

// ---------------- grouped down-GEMM + weighted bf16 store (compact) ----------------
// BM=256, BN=256, BK=64, K=512, 512 thr (8 waves 4Mx2N, 64x128 per wave),
// double-buffered LDS (2 x {A 32K | B 32K}), depth-1 prefetch.
__global__ __launch_bounds__(512, 2) void k_down(const ushort* __restrict__ act,
                                                 const ushort* __restrict__ wdT,
                                                 ushort* __restrict__ ybuf,
                                                 const float* __restrict__ wgt,
                                                 const int* __restrict__ meta) {
    __shared__ __align__(16) char smem[131072];
    int bid = blockIdx.x;
    int s = (bid & 7) * CPX + (bid >> 3);
    int rb = s >> 2, cb = s & 3;
    if (rb >= meta[17]) return;
    int e = meta[32 + rb], rloc = meta[160 + rb], abrow = meta[288 + rb];
    int ne = meta[e];
    int tid = threadIdx.x, lane = tid & 63, wave = tid >> 6;

    int srow = tid >> 3;
    int col16 = (tid & 7) << 4;
    int swz = col16 ^ ((srow & 7) << 4);
    const char* abase = (const char*)act + (size_t)abrow * 1024;
    const char* bbase = (const char*)wdT + (size_t)e * 1048576 + (size_t)cb * 256 * 1024;
    int ldsl = wave * 1024;

    int wr = wave >> 1, wc = wave & 1;
    int lr = lane & 15, lk = lane >> 4;
    int aOff = (wr * 64 + lr) * 128;
    int bOff = (wc * 128 + lr) * 128;
    int kp0 = (lk * 16) ^ ((lr & 7) << 4);
    int kp1 = (64 + lk * 16) ^ ((lr & 7) << 4);

    f32x4 acc[4][8];
#pragma unroll
    for (int m = 0; m < 4; m++)
#pragma unroll
        for (int n = 0; n < 8; n++) acc[m][n] = (f32x4){0.f, 0.f, 0.f, 0.f};

#define STAGE_DN(KT, D)                                                                  \
    {                                                                                    \
        char* base = smem + (D) * 65536;                                                 \
        int kB = (KT) * 128;                                                             \
        _Pragma("unroll")                                                                \
        for (int i = 0; i < 4; i++)                                                      \
            gload16(abase + (size_t)(i * 64 + srow) * 1024 + kB + swz,                   \
                    base + i * 8192 + ldsl);                                             \
        _Pragma("unroll")                                                                \
        for (int i = 0; i < 4; i++)                                                      \
            gload16(bbase + (size_t)(i * 64 + srow) * 1024 + kB + swz,                   \
                    base + 32768 + i * 8192 + ldsl);                                     \
    }

    STAGE_DN(0, 0);
    asm volatile("s_waitcnt vmcnt(0)" ::: "memory");
    __syncthreads();
    int cur = 0;
#pragma unroll 1
    for (int kt = 0; kt < 8; ++kt) {
        if (kt < 7) STAGE_DN(kt + 1, cur ^ 1);
        const char* A = smem + cur * 65536;
        const char* B = A + 32768;
#pragma unroll
        for (int kk = 0; kk < 2; kk++) {
            int kp = kk ? kp1 : kp0;
            bf16x8 a[4], b[8];
#pragma unroll
            for (int m = 0; m < 4; m++) a[m] = *(const bf16x8*)(A + aOff + m * 2048 + kp);
#pragma unroll
            for (int n = 0; n < 8; n++) b[n] = *(const bf16x8*)(B + bOff + n * 2048 + kp);
#pragma unroll
            for (int m = 0; m < 4; m++)
#pragma unroll
                for (int n = 0; n < 8; n++)
                    acc[m][n] = __builtin_amdgcn_mfma_f32_16x16x32_bf16(a[m], b[n], acc[m][n], 0, 0, 0);
        }
        asm volatile("s_waitcnt vmcnt(0)" ::: "memory");
        __syncthreads();
        cur ^= 1;
    }
    // scale by router weight, stage bf16 tile [256][256] in LDS (128KB)
    const int lb = e * CAP + rloc;
    ushort* yl = (ushort*)smem;
#pragma unroll
    for (int m = 0; m < 4; m++)
#pragma unroll
        for (int j = 0; j < 4; j++) {
            int row = wr * 64 + m * 16 + lk * 4 + j;
            float w = wgt[lb + row];
#pragma unroll
            for (int n = 0; n < 8; n++) {
                int col = wc * 128 + n * 16 + lr;
                yl[row * 256 + col] = f2bf(acc[m][n][j] * w);
            }
        }
    __syncthreads();
#pragma unroll
    for (int p = 0; p < 16; p++) {
        int c = p * 512 + tid;
        int row = c >> 5, off = (c & 31) << 4;
        if (rloc + row < ne)
            *(uint4*)((char*)ybuf + (size_t)(abrow + row) * 2048 + cb * 512 + off) =
                *(const uint4*)((const char*)yl + row * 512 + off);
    }
#undef STAGE_DN
}

// ---------------- per-token combine ----------------
__global__ __launch_bounds__(256) void k_combine(const ushort* __restrict__ y,
                                                 const int2* __restrict__ ia,
                                                 const int2* __restrict__ ib,
                                                 const int* __restrict__ meta,
                                                 float* __restrict__ out) {
    int t = blockIdx.x;
    int2 a = ia[t], b = ib[t];
    int r0 = (meta[416 + a.x] + a.y) << 10;
    int r1 = (meta[416 + b.x] + b.y) << 10;
    int rs = (meta[432] + t) << 10;
    int c = threadIdx.x << 2;
    ushort4 va = *(const ushort4*)(y + r0 + c);
    ushort4 vb = *(const ushort4*)(y + r1 + c);
    ushort4 vs = *(const ushort4*)(y + rs + c);
    float4 o;
    o.x = bf2f(va.x) + bf2f(vb.x) + bf2f(vs.x);
    o.y = bf2f(va.y) + bf2f(vb.y) + bf2f(vs.y);
    o.z = bf2f(va.z) + bf2f(vb.z) + bf2f(vs.z);
    o.w = bf2f(va.w) + bf2f(vb.w) + bf2f(vs.w);
    *(float4*)(out + ((size_t)t << 10) + c) = o;
}

extern "C" void kernel_launch(void* const* d_in, const int* in_sizes, int n_in,
                              void* d_out, int out_size, void* d_ws, size_t ws_size,
                              hipStream_t stream) {
    const float* x    = (const float*)d_in[0];
    const float* Wr   = (const float*)d_in[1];
    const float* Wup  = (const float*)d_in[2];
    const float* Wdn  = (const float*)d_in[3];
    const float* Wsup = (const float*)d_in[4];
    const float* Wsdn = (const float*)d_in[5];
    float* out = (float*)d_out;
    float* probs = out + (size_t)T_TOK * HD;

    if (ws_size < WS_NEEDED) return;

    char* ws = (char*)d_ws;
    ushort* xb    = (ushort*)(ws + OFF_XBF);
    ushort* wupT  = (ushort*)(ws + OFF_WUPT);
    ushort* wdT   = (ushort*)(ws + OFF_WDT);
    ushort* act   = (ushort*)(ws + OFF_ACT);
    int2*   inva  = (int2*)(ws + OFF_EIDX);
    int2*   invb  = (int2*)(ws + OFF_EW);
    int*    tok   = (int*)(ws + OFF_TOK);
    float*  wgt   = (float*)(ws + OFF_WGT);
    int*    meta  = (int*)(ws + OFF_META);
    ushort* ybuf  = (ushort*)(ws + OFF_XBF);   // aliases xb+wupT (dead after k_up)

    hipMemsetAsync(meta, 0, 4096, stream);

    // 8192 router blocks + 17*1024 W_up-transpose blocks + 17*512 W_dn-transpose blocks
    k_prep<<<T_TOK + NET * 1024 + NET * 512, 256, 0, stream>>>(
        x, Wr, Wup, Wsup, Wdn, Wsdn, probs, inva, invb, xb, wupT, wdT, tok, wgt, meta);
    k_finalize<<<1, 256, 0, stream>>>(meta, tok, wgt);
    k_up<<<MAXWG, 512, 0, stream>>>(xb, wupT, act, tok, meta);
    k_down<<<MAXWG, 512, 0, stream>>>(act, wdT, ybuf, wgt, meta);
    k_combine<<<T_TOK, 256, 0, stream>>>(ybuf, inva, invb, meta, out);
}

// Round 6
// 242.146 us; speedup vs baseline: 1.3862x; 1.3862x over previous
//
#include <hip/hip_runtime.h>
#include <stdint.h>

#define T_TOK 8192
#define HD 1024
#define NE 16
#define NET 17
#define FD 512
#define CAP 8448            // max tokens/expert 8192 + 255 pad (256-row blocks)
#define MAXWG 448           // 112 row-blocks x 4 col-blocks
#define CPX 56              // MAXWG / 8 XCDs

typedef unsigned int uint;
typedef unsigned short ushort;
typedef __attribute__((ext_vector_type(8))) __bf16 bf16x8;
typedef __attribute__((ext_vector_type(4))) float f32x4;

// ws layout (bytes)
#define OFF_XBF   0ull            // 16 MB   (dead after k_up -> ybuf)
#define OFF_WUPT  16777216ull     // 35.65MB (dead after k_up -> ybuf)
#define OFF_WDT   52428800ull     // 17.83MB
#define OFF_ACT   70254592ull     // 24576 x 1024 B = 25.17MB (compact rows)
#define OFF_EIDX  95420416ull     // inv_a (e0,p0) per token
#define OFF_EW    95485952ull     // inv_b (e1,p1) per token
#define OFF_TOK   95551488ull     // 17*CAP ints
#define OFF_WGT   96125952ull
#define OFF_META  96700416ull
#define WS_NEEDED (OFF_META + 4096ull)
// ybuf: compact 24576 rows x 2048 B = 50,331,648 < OFF_WDT.

// meta: [0..16]=cnt (16=shared=8192), [17]=nRB, [32..144)=rbE, [160..272)=rbLoc,
//       [288..400)=rbRow (compact base), [416..433)=ybase per expert

__device__ __forceinline__ ushort f2bf(float f) {
    uint u = __float_as_uint(f);
    u += 0x7FFFu + ((u >> 16) & 1u);
    return (ushort)(u >> 16);
}
__device__ __forceinline__ float bf2f(ushort u) {
    return __uint_as_float(((uint)u) << 16);
}
__device__ __forceinline__ void gload16(const void* g, void* l) {
    __builtin_amdgcn_global_load_lds(
        (const __attribute__((address_space(1))) void*)g,
        (__attribute__((address_space(3))) void*)l, 16, 0, 0);
}

// ---------------- router (fp32 logits; fused x->bf16 convert + softmax + top2 + bucket) ----------------
// 512 blocks x 16 tokens. LDS holds FP32 x (selection must match fp32 reference:
// bf16 logits flip top-2 for ~dozens of tokens -> 0.3 absmax; round-5 lesson).
__global__ __launch_bounds__(256) void k_router(const float* __restrict__ x,
                                                const float* __restrict__ Wr,
                                                float* __restrict__ probs,
                                                int2* __restrict__ inva,
                                                int2* __restrict__ invb,
                                                ushort* __restrict__ xb,
                                                int* __restrict__ tok,
                                                float* __restrict__ wgt,
                                                int* __restrict__ meta) {
    __shared__ __align__(16) float xs[16][1032];   // stride 1032: groups 8 banks apart
    int tid = threadIdx.x;
    int t0 = blockIdx.x * 16;
    // phase 1: load 16 token rows (fp32 -> LDS), convert bf16 -> xb
#pragma unroll 4
    for (int p = 0; p < 16; ++p) {
        float4 v = *(const float4*)(x + (size_t)(t0 + p) * HD + tid * 4);
        ushort4 c;
        c.x = f2bf(v.x); c.y = f2bf(v.y); c.z = f2bf(v.z); c.w = f2bf(v.w);
        *(ushort4*)(xb + (size_t)(t0 + p) * HD + tid * 4) = c;
        *(float4*)(&xs[p][tid * 4]) = v;
    }
    __syncthreads();
    // phase 2: fp32 logit for (token ti, expert e)
    int ti = tid >> 4, e = tid & 15;
    const float* xr = xs[ti];
    float s = 0.f;
#pragma unroll 4
    for (int k = 0; k < 1024; k += 4) {
        float4 xv = *(const float4*)(xr + k);
        s = fmaf(xv.x, Wr[(k + 0) * NE + e], s);
        s = fmaf(xv.y, Wr[(k + 1) * NE + e], s);
        s = fmaf(xv.z, Wr[(k + 2) * NE + e], s);
        s = fmaf(xv.w, Wr[(k + 3) * NE + e], s);
    }
    // phase 3: softmax + top2 within 16-lane group
    float m = s;
#pragma unroll
    for (int w = 1; w < 16; w <<= 1) m = fmaxf(m, __shfl_xor(m, w));
    float p = __expf(s - m);
    float sum = p;
#pragma unroll
    for (int w = 1; w < 16; w <<= 1) sum += __shfl_xor(sum, w);
    p /= sum;
    int t = t0 + ti;
    probs[(size_t)t * NE + e] = p;
    float m1 = p;
#pragma unroll
    for (int w = 1; w < 16; w <<= 1) m1 = fmaxf(m1, __shfl_xor(m1, w));
    int g4 = (tid & 63) >> 4;
    unsigned long long bal = __ballot(p == m1);
    int i1 = __ffs((int)((bal >> (g4 * 16)) & 0xFFFFu)) - 1;
    float p2v = (e == i1) ? -1.f : p;
    float m2 = p2v;
#pragma unroll
    for (int w = 1; w < 16; w <<= 1) m2 = fmaxf(m2, __shfl_xor(m2, w));
    bal = __ballot(p2v == m2);
    int i2 = __ffs((int)((bal >> (g4 * 16)) & 0xFFFFu)) - 1;
    if (e == 0) {
        float inv2 = 1.f / (m1 + m2 + 1e-9f);
        int p0 = atomicAdd(&meta[i1], 1);
        tok[i1 * CAP + p0] = t; wgt[i1 * CAP + p0] = m1 * inv2;
        int p1 = atomicAdd(&meta[i2], 1);
        tok[i2 * CAP + p1] = t; wgt[i2 * CAP + p1] = m2 * inv2;
        tok[16 * CAP + t] = t; wgt[16 * CAP + t] = 1.f;
        inva[t] = make_int2(i1, p0);
        invb[t] = make_int2(i2, p1);
    }
}

// ---------------- W_up [E][H][2F] fp32 (+shared) -> wupT [17][2F][H] bf16, 64x64 tiles ----------------
__global__ __launch_bounds__(256) void k_tup(const float* __restrict__ Wup,
                                             const float* __restrict__ Wsup,
                                             ushort* __restrict__ dst) {
    __shared__ __align__(16) float tile[64][68];
    int bid = blockIdx.x;
    int e = bid >> 8, rem = bid & 255;
    int h0 = (rem >> 4) * 64, n0 = (rem & 15) * 64;
    const float* src = (e < 16) ? (Wup + (size_t)e * HD * 1024) : Wsup;
    int tid = threadIdx.x;
    int rr = tid >> 4, cc = (tid & 15) * 4;
#pragma unroll
    for (int q = 0; q < 4; ++q) {
        float4 v = *(const float4*)(src + (size_t)(h0 + q * 16 + rr) * 1024 + n0 + cc);
        *(float4*)(&tile[q * 16 + rr][cc]) = v;
    }
    __syncthreads();
#pragma unroll
    for (int q = 0; q < 4; ++q) {
        int nl = q * 16 + rr;
        ushort4 o;
        o.x = f2bf(tile[cc + 0][nl]);
        o.y = f2bf(tile[cc + 1][nl]);
        o.z = f2bf(tile[cc + 2][nl]);
        o.w = f2bf(tile[cc + 3][nl]);
        *(ushort4*)(dst + (size_t)e * 1048576 + (size_t)(n0 + nl) * 1024 + h0 + cc) = o;
    }
}

// ---------------- W_down [E][F][H] fp32 (+shared) -> wdT [17][H][F] bf16, 64x64 tiles ----------------
__global__ __launch_bounds__(256) void k_tdn(const float* __restrict__ Wdn,
                                             const float* __restrict__ Wsdn,
                                             ushort* __restrict__ dst) {
    __shared__ __align__(16) float tile[64][68];
    int bid = blockIdx.x;
    int e = bid >> 7, rem = bid & 127;
    int f0 = (rem >> 4) * 64, h0 = (rem & 15) * 64;
    const float* src = (e < 16) ? (Wdn + (size_t)e * FD * HD) : Wsdn;
    int tid = threadIdx.x;
    int rr = tid >> 4, cc = (tid & 15) * 4;
#pragma unroll
    for (int q = 0; q < 4; ++q) {
        float4 v = *(const float4*)(src + (size_t)(f0 + q * 16 + rr) * 1024 + h0 + cc);
        *(float4*)(&tile[q * 16 + rr][cc]) = v;
    }
    __syncthreads();
#pragma unroll
    for (int q = 0; q < 4; ++q) {
        int hl = q * 16 + rr;
        ushort4 o;
        o.x = f2bf(tile[cc + 0][hl]);
        o.y = f2bf(tile[cc + 1][hl]);
        o.z = f2bf(tile[cc + 2][hl]);
        o.w = f2bf(tile[cc + 3][hl]);
        *(ushort4*)(dst + (size_t)e * 524288 + (size_t)(h0 + hl) * 512 + f0 + cc) = o;
    }
}

// ---------------- finalize: build 256-row blocks, zero pad slots ----------------
__global__ void k_finalize(int* __restrict__ meta, int* __restrict__ tok,
                           float* __restrict__ wgt) {
    __shared__ int sN[NET], sPad[NET];
    int tid = threadIdx.x;
    if (tid == 0) {
        meta[16] = T_TOK;   // shared-expert count
        int idx = 0, yoff = 0;
        for (int e = 0; e < NET; e++) {
            int n = meta[e];
            int padded = (n + 255) & ~255;
            sN[e] = n; sPad[e] = padded;
            meta[416 + e] = yoff;
            for (int i = 0; i < padded; i += 256) {
                meta[32 + idx] = e; meta[160 + idx] = i; meta[288 + idx] = yoff + i; idx++;
            }
            yoff += n;
        }
        meta[17] = idx;
    }
    __syncthreads();
    for (int e = 0; e < NET; e++)
        for (int i = sN[e] + tid; i < sPad[e]; i += 256) {
            tok[e * CAP + i] = 0; wgt[e * CAP + i] = 0.f;
        }
}

// ---------------- grouped up-GEMM + SiLU ----------------
// BM=256, cols 128 gate + 128 up per block, BK=64, 512 thr (8 waves 4Mx2N),
// double-buffered LDS (2 x {A 32K | Bg 16K | Bu 16K}), depth-1 prefetch.
__global__ __launch_bounds__(512, 2) void k_up(const ushort* __restrict__ xb,
                                               const ushort* __restrict__ wupT,
                                               ushort* __restrict__ act,
                                               const int* __restrict__ tok,
                                               const int* __restrict__ meta) {
    __shared__ __align__(16) char smem[131072];
    int bid = blockIdx.x;
    int s = (bid & 7) * CPX + (bid >> 3);     // XCD swizzle: 4 cb of one rb per XCD
    int rb = s >> 2, cb = s & 3;
    if (rb >= meta[17]) return;
    int e = meta[32 + rb], rloc = meta[160 + rb], abrow = meta[288 + rb];
    int ne = meta[e];
    int tid = threadIdx.x, lane = tid & 63, wave = tid >> 6;

    int srow = tid >> 3;                       // 0..63 (row within 64-row issue)
    int col16 = (tid & 7) << 4;
    int swz = col16 ^ ((srow & 7) << 4);
    const int listBase = e * CAP + rloc;
    int tokr[4];
#pragma unroll
    for (int i = 0; i < 4; i++) tokr[i] = tok[listBase + i * 64 + srow];
    const char* xbase = (const char*)xb;
    const char* wb = (const char*)wupT + (size_t)e * 2097152;
    int ldsl = wave * 1024;                    // wave-uniform LDS slot within each 8KB issue

    int wr = wave >> 1, wc = wave & 1;
    int lr = lane & 15, lk = lane >> 4;
    int aOff = (wr * 64 + lr) * 128;
    int bOff = (wc * 64 + lr) * 128;
    int kp0 = (lk * 16) ^ ((lr & 7) << 4);
    int kp1 = (64 + lk * 16) ^ ((lr & 7) << 4);

    f32x4 accg[4][4], accu[4][4];
#pragma unroll
    for (int m = 0; m < 4; m++)
#pragma unroll
        for (int n = 0; n < 4; n++) {
            accg[m][n] = (f32x4){0.f, 0.f, 0.f, 0.f};
            accu[m][n] = (f32x4){0.f, 0.f, 0.f, 0.f};
        }

#define STAGE_UP(KT, D)                                                                   \
    {                                                                                     \
        char* base = smem + (D) * 65536;                                                  \
        int kB = (KT) * 128;                                                              \
        _Pragma("unroll")                                                                 \
        for (int i = 0; i < 4; i++)                                                       \
            gload16(xbase + (size_t)tokr[i] * 2048 + kB + swz, base + i * 8192 + ldsl);   \
        _Pragma("unroll")                                                                 \
        for (int i = 0; i < 2; i++)                                                       \
            gload16(wb + (size_t)(cb * 128 + i * 64 + srow) * 2048 + kB + swz,            \
                    base + 32768 + i * 8192 + ldsl);                                      \
        _Pragma("unroll")                                                                 \
        for (int i = 0; i < 2; i++)                                                       \
            gload16(wb + (size_t)(512 + cb * 128 + i * 64 + srow) * 2048 + kB + swz,      \
                    base + 49152 + i * 8192 + ldsl);                                      \
    }

    STAGE_UP(0, 0);
    asm volatile("s_waitcnt vmcnt(0)" ::: "memory");
    __syncthreads();
    int cur = 0;
#pragma unroll 1
    for (int kt = 0; kt < 16; ++kt) {
        if (kt < 15) STAGE_UP(kt + 1, cur ^ 1);
        const char* A  = smem + cur * 65536;
        const char* Bg = A + 32768;
        const char* Bu = A + 49152;
#pragma unroll
        for (int kk = 0; kk < 2; kk++) {
            int kp = kk ? kp1 : kp0;
            bf16x8 a[4], bg[4], bu[4];
#pragma unroll
            for (int m = 0; m < 4; m++) a[m] = *(const bf16x8*)(A + aOff + m * 2048 + kp);
#pragma unroll
            for (int n = 0; n < 4; n++) bg[n] = *(const bf16x8*)(Bg + bOff + n * 2048 + kp);
#pragma unroll
            for (int n = 0; n < 4; n++) bu[n] = *(const bf16x8*)(Bu + bOff + n * 2048 + kp);
#pragma unroll
            for (int m = 0; m < 4; m++)
#pragma unroll
                for (int n = 0; n < 4; n++) {
                    accg[m][n] = __builtin_amdgcn_mfma_f32_16x16x32_bf16(a[m], bg[n], accg[m][n], 0, 0, 0);
                    accu[m][n] = __builtin_amdgcn_mfma_f32_16x16x32_bf16(a[m], bu[n], accu[m][n], 0, 0, 0);
                }
        }
        asm volatile("s_waitcnt vmcnt(0)" ::: "memory");
        __syncthreads();
        cur ^= 1;
    }
    // SiLU(gate)*up -> bf16, stage in LDS [256][128]
    ushort* actl = (ushort*)smem;
#pragma unroll
    for (int m = 0; m < 4; m++)
#pragma unroll
        for (int n = 0; n < 4; n++)
#pragma unroll
            for (int j = 0; j < 4; j++) {
                float gv = accg[m][n][j];
                float uv = accu[m][n][j];
                float av = (gv / (1.f + __expf(-gv))) * uv;
                int row = wr * 64 + m * 16 + lk * 4 + j;
                int col = wc * 64 + n * 16 + lr;
                actl[row * 128 + col] = f2bf(av);
            }
    __syncthreads();
#pragma unroll
    for (int p = 0; p < 8; p++) {
        int c = p * 512 + tid;
        int row = c >> 4, off = (c & 15) << 4;
        if (rloc + row < ne)
            *(uint4*)((char*)act + (size_t)(abrow + row) * 1024 + cb * 256 + off) =
                *(const uint4*)((const char*)actl + row * 256 + off);
    }
#undef STAGE_UP
}

// ---------------- grouped down-GEMM + weighted bf16 store (compact) ----------------
// BM=256, BN=256, BK=64, K=512, 512 thr (8 waves 4Mx2N, 64x128 per wave),
// double-buffered LDS (2 x {A 32K | B 32K}), depth-1 prefetch.
__global__ __launch_bounds__(512, 2) void k_down(const ushort* __restrict__ act,
                                                 const ushort* __restrict__ wdT,
                                                 ushort* __restrict__ ybuf,
                                                 const float* __restrict__ wgt,
                                                 const int* __restrict__ meta) {
    __shared__ __align__(16) char smem[131072];
    int bid = blockIdx.x;
    int s = (bid & 7) * CPX + (bid >> 3);
    int rb = s >> 2, cb = s & 3;
    if (rb >= meta[17]) return;
    int e = meta[32 + rb], rloc = meta[160 + rb], abrow = meta[288 + rb];
    int ne = meta[e];
    int tid = threadIdx.x, lane = tid & 63, wave = tid >> 6;

    int srow = tid >> 3;
    int col16 = (tid & 7) << 4;
    int swz = col16 ^ ((srow & 7) << 4);
    const char* abase = (const char*)act + (size_t)abrow * 1024;
    const char* bbase = (const char*)wdT + (size_t)e * 1048576 + (size_t)cb * 256 * 1024;
    int ldsl = wave * 1024;

    int wr = wave >> 1, wc = wave & 1;
    int lr = lane & 15, lk = lane >> 4;
    int aOff = (wr * 64 + lr) * 128;
    int bOff = (wc * 128 + lr) * 128;
    int kp0 = (lk * 16) ^ ((lr & 7) << 4);
    int kp1 = (64 + lk * 16) ^ ((lr & 7) << 4);

    f32x4 acc[4][8];
#pragma unroll
    for (int m = 0; m < 4; m++)
#pragma unroll
        for (int n = 0; n < 8; n++) acc[m][n] = (f32x4){0.f, 0.f, 0.f, 0.f};

#define STAGE_DN(KT, D)                                                                  \
    {                                                                                    \
        char* base = smem + (D) * 65536;                                                 \
        int kB = (KT) * 128;                                                             \
        _Pragma("unroll")                                                                \
        for (int i = 0; i < 4; i++)                                                      \
            gload16(abase + (size_t)(i * 64 + srow) * 1024 + kB + swz,                   \
                    base + i * 8192 + ldsl);                                             \
        _Pragma("unroll")                                                                \
        for (int i = 0; i < 4; i++)                                                      \
            gload16(bbase + (size_t)(i * 64 + srow) * 1024 + kB + swz,                   \
                    base + 32768 + i * 8192 + ldsl);                                     \
    }

    STAGE_DN(0, 0);
    asm volatile("s_waitcnt vmcnt(0)" ::: "memory");
    __syncthreads();
    int cur = 0;
#pragma unroll 1
    for (int kt = 0; kt < 8; ++kt) {
        if (kt < 7) STAGE_DN(kt + 1, cur ^ 1);
        const char* A = smem + cur * 65536;
        const char* B = A + 32768;
#pragma unroll
        for (int kk = 0; kk < 2; kk++) {
            int kp = kk ? kp1 : kp0;
            bf16x8 a[4], b[8];
#pragma unroll
            for (int m = 0; m < 4; m++) a[m] = *(const bf16x8*)(A + aOff + m * 2048 + kp);
#pragma unroll
            for (int n = 0; n < 8; n++) b[n] = *(const bf16x8*)(B + bOff + n * 2048 + kp);
#pragma unroll
            for (int m = 0; m < 4; m++)
#pragma unroll
                for (int n = 0; n < 8; n++)
                    acc[m][n] = __builtin_amdgcn_mfma_f32_16x16x32_bf16(a[m], b[n], acc[m][n], 0, 0, 0);
        }
        asm volatile("s_waitcnt vmcnt(0)" ::: "memory");
        __syncthreads();
        cur ^= 1;
    }
    // scale by router weight, stage bf16 tile [256][256] in LDS (128KB)
    const int lb = e * CAP + rloc;
    ushort* yl = (ushort*)smem;
#pragma unroll
    for (int m = 0; m < 4; m++)
#pragma unroll
        for (int j = 0; j < 4; j++) {
            int row = wr * 64 + m * 16 + lk * 4 + j;
            float w = wgt[lb + row];
#pragma unroll
            for (int n = 0; n < 8; n++) {
                int col = wc * 128 + n * 16 + lr;
                yl[row * 256 + col] = f2bf(acc[m][n][j] * w);
            }
        }
    __syncthreads();
#pragma unroll
    for (int p = 0; p < 16; p++) {
        int c = p * 512 + tid;
        int row = c >> 5, off = (c & 31) << 4;
        if (rloc + row < ne)
            *(uint4*)((char*)ybuf + (size_t)(abrow + row) * 2048 + cb * 512 + off) =
                *(const uint4*)((const char*)yl + row * 512 + off);
    }
#undef STAGE_DN
}

// ---------------- per-token combine ----------------
__global__ __launch_bounds__(256) void k_combine(const ushort* __restrict__ y,
                                                 const int2* __restrict__ ia,
                                                 const int2* __restrict__ ib,
                                                 const int* __restrict__ meta,
                                                 float* __restrict__ out) {
    int t = blockIdx.x;
    int2 a = ia[t], b = ib[t];
    int r0 = (meta[416 + a.x] + a.y) << 10;
    int r1 = (meta[416 + b.x] + b.y) << 10;
    int rs = (meta[432] + t) << 10;
    int c = threadIdx.x << 2;
    ushort4 va = *(const ushort4*)(y + r0 + c);
    ushort4 vb = *(const ushort4*)(y + r1 + c);
    ushort4 vs = *(const ushort4*)(y + rs + c);
    float4 o;
    o.x = bf2f(va.x) + bf2f(vb.x) + bf2f(vs.x);
    o.y = bf2f(va.y) + bf2f(vb.y) + bf2f(vs.y);
    o.z = bf2f(va.z) + bf2f(vb.z) + bf2f(vs.z);
    o.w = bf2f(va.w) + bf2f(vb.w) + bf2f(vs.w);
    *(float4*)(out + ((size_t)t << 10) + c) = o;
}

extern "C" void kernel_launch(void* const* d_in, const int* in_sizes, int n_in,
                              void* d_out, int out_size, void* d_ws, size_t ws_size,
                              hipStream_t stream) {
    const float* x    = (const float*)d_in[0];
    const float* Wr   = (const float*)d_in[1];
    const float* Wup  = (const float*)d_in[2];
    const float* Wdn  = (const float*)d_in[3];
    const float* Wsup = (const float*)d_in[4];
    const float* Wsdn = (const float*)d_in[5];
    float* out = (float*)d_out;
    float* probs = out + (size_t)T_TOK * HD;

    if (ws_size < WS_NEEDED) return;

    char* ws = (char*)d_ws;
    ushort* xb    = (ushort*)(ws + OFF_XBF);
    ushort* wupT  = (ushort*)(ws + OFF_WUPT);
    ushort* wdT   = (ushort*)(ws + OFF_WDT);
    ushort* act   = (ushort*)(ws + OFF_ACT);
    int2*   inva  = (int2*)(ws + OFF_EIDX);
    int2*   invb  = (int2*)(ws + OFF_EW);
    int*    tok   = (int*)(ws + OFF_TOK);
    float*  wgt   = (float*)(ws + OFF_WGT);
    int*    meta  = (int*)(ws + OFF_META);
    ushort* ybuf  = (ushort*)(ws + OFF_XBF);   // aliases xb+wupT (dead after k_up)

    hipMemsetAsync(meta, 0, 4096, stream);

    k_tup<<<NET * 256, 256, 0, stream>>>(Wup, Wsup, wupT);
    k_tdn<<<NET * 128, 256, 0, stream>>>(Wdn, Wsdn, wdT);
    k_router<<<T_TOK / 16, 256, 0, stream>>>(x, Wr, probs, inva, invb, xb, tok, wgt, meta);
    k_finalize<<<1, 256, 0, stream>>>(meta, tok, wgt);
    k_up<<<MAXWG, 512, 0, stream>>>(xb, wupT, act, tok, meta);
    k_down<<<MAXWG, 512, 0, stream>>>(act, wdT, ybuf, wgt, meta);
    k_combine<<<T_TOK, 256, 0, stream>>>(ybuf, inva, invb, meta, out);
}

// Round 7
// 236.706 us; speedup vs baseline: 1.4180x; 1.0230x over previous
//
#include <hip/hip_runtime.h>
#include <stdint.h>

#define T_TOK 8192
#define HD 1024
#define NE 16
#define NET 17
#define FD 512
#define CAP 8448            // max tokens/expert 8192 + 255 pad (256-row blocks)
#define MAXWG 448           // 112 row-blocks x 4 col-blocks
#define CPX 56              // MAXWG / 8 XCDs

typedef unsigned int uint;
typedef unsigned short ushort;
typedef __attribute__((ext_vector_type(8))) __bf16 bf16x8;
typedef __attribute__((ext_vector_type(4))) float f32x4;

// ws layout (bytes)
#define OFF_XBF   0ull            // 16 MB   (dead after k_up -> ybuf)
#define OFF_WUPT  16777216ull     // 35.65MB (dead after k_up -> ybuf)
#define OFF_WDT   52428800ull     // 17.83MB
#define OFF_ACT   70254592ull     // 24576 x 1024 B = 25.17MB (compact rows)
#define OFF_EIDX  95420416ull     // inv_a (e0,p0) per token
#define OFF_EW    95485952ull     // inv_b (e1,p1) per token
#define OFF_TOK   95551488ull     // 17*CAP ints
#define OFF_WGT   96125952ull
#define OFF_META  96700416ull
#define WS_NEEDED (OFF_META + 4096ull)
// ybuf: compact 24576 rows x 2048 B = 50,331,648 < OFF_WDT.

// meta: [0..16]=cnt (16=shared=8192), [17]=nRB, [32..144)=rbE, [160..272)=rbLoc,
//       [288..400)=rbRow (compact base), [416..433)=ybase per expert

__device__ __forceinline__ ushort f2bf(float f) {
    uint u = __float_as_uint(f);
    u += 0x7FFFu + ((u >> 16) & 1u);
    return (ushort)(u >> 16);
}
__device__ __forceinline__ float bf2f(ushort u) {
    return __uint_as_float(((uint)u) << 16);
}
__device__ __forceinline__ void gload16(const void* g, void* l) {
    __builtin_amdgcn_global_load_lds(
        (const __attribute__((address_space(1))) void*)g,
        (__attribute__((address_space(3))) void*)l, 16, 0, 0);
}

// ---------------- router (fp32; Wr staged in LDS, x via same-address global broadcast) ----------------
// Round-6 lesson: reading Wr from global inside the k-loop serialized at ~1
// L2-latency/iteration (106us). Wr now lives in LDS (64KB, conflict-free reads);
// x comes from global (16 lanes/group read the SAME float4 -> 1 fetch, L1-hot
// from the phase-1 conversion). fp32 math throughout (round-5 lesson: bf16
// logits flip top-2 selections -> 0.3 absmax).
__global__ __launch_bounds__(256) void k_router(const float* __restrict__ x,
                                                const float* __restrict__ Wr,
                                                float* __restrict__ probs,
                                                int2* __restrict__ inva,
                                                int2* __restrict__ invb,
                                                ushort* __restrict__ xb,
                                                int* __restrict__ tok,
                                                float* __restrict__ wgt,
                                                int* __restrict__ meta) {
    __shared__ __align__(16) float wr_s[HD * NE];   // 64 KB
    int tid = threadIdx.x;
    int t0 = blockIdx.x * 16;
    // stage Wr -> LDS (16 float4 per thread)
#pragma unroll
    for (int i = 0; i < 16; ++i) {
        int idx = (i * 256 + tid) * 4;
        *(float4*)(&wr_s[idx]) = *(const float4*)(Wr + idx);
    }
    // phase 1: convert 16 token rows to bf16 -> xb (also warms L1 with x rows)
#pragma unroll 4
    for (int p = 0; p < 16; ++p) {
        float4 v = *(const float4*)(x + (size_t)(t0 + p) * HD + tid * 4);
        ushort4 c;
        c.x = f2bf(v.x); c.y = f2bf(v.y); c.z = f2bf(v.z); c.w = f2bf(v.w);
        *(ushort4*)(xb + (size_t)(t0 + p) * HD + tid * 4) = c;
    }
    __syncthreads();
    // phase 2: fp32 logit for (token ti, expert e); x float4 broadcast per group
    int ti = tid >> 4, e = tid & 15;
    int t = t0 + ti;
    const float* xg = x + (size_t)t * HD;
    float s0 = 0.f, s1 = 0.f, s2 = 0.f, s3 = 0.f;
#pragma unroll 4
    for (int k = 0; k < 1024; k += 16) {
        float4 a = *(const float4*)(xg + k);
        float4 b = *(const float4*)(xg + k + 4);
        float4 c = *(const float4*)(xg + k + 8);
        float4 d = *(const float4*)(xg + k + 12);
        s0 = fmaf(a.x, wr_s[(k + 0) * NE + e], s0);
        s1 = fmaf(a.y, wr_s[(k + 1) * NE + e], s1);
        s2 = fmaf(a.z, wr_s[(k + 2) * NE + e], s2);
        s3 = fmaf(a.w, wr_s[(k + 3) * NE + e], s3);
        s0 = fmaf(b.x, wr_s[(k + 4) * NE + e], s0);
        s1 = fmaf(b.y, wr_s[(k + 5) * NE + e], s1);
        s2 = fmaf(b.z, wr_s[(k + 6) * NE + e], s2);
        s3 = fmaf(b.w, wr_s[(k + 7) * NE + e], s3);
        s0 = fmaf(c.x, wr_s[(k + 8) * NE + e], s0);
        s1 = fmaf(c.y, wr_s[(k + 9) * NE + e], s1);
        s2 = fmaf(c.z, wr_s[(k + 10) * NE + e], s2);
        s3 = fmaf(c.w, wr_s[(k + 11) * NE + e], s3);
        s0 = fmaf(d.x, wr_s[(k + 12) * NE + e], s0);
        s1 = fmaf(d.y, wr_s[(k + 13) * NE + e], s1);
        s2 = fmaf(d.z, wr_s[(k + 14) * NE + e], s2);
        s3 = fmaf(d.w, wr_s[(k + 15) * NE + e], s3);
    }
    float s = (s0 + s1) + (s2 + s3);
    // phase 3: softmax + top2 within 16-lane group
    float m = s;
#pragma unroll
    for (int w = 1; w < 16; w <<= 1) m = fmaxf(m, __shfl_xor(m, w));
    float p = __expf(s - m);
    float sum = p;
#pragma unroll
    for (int w = 1; w < 16; w <<= 1) sum += __shfl_xor(sum, w);
    p /= sum;
    probs[(size_t)t * NE + e] = p;
    float m1 = p;
#pragma unroll
    for (int w = 1; w < 16; w <<= 1) m1 = fmaxf(m1, __shfl_xor(m1, w));
    int g4 = (tid & 63) >> 4;
    unsigned long long bal = __ballot(p == m1);
    int i1 = __ffs((int)((bal >> (g4 * 16)) & 0xFFFFu)) - 1;
    float p2v = (e == i1) ? -1.f : p;
    float m2 = p2v;
#pragma unroll
    for (int w = 1; w < 16; w <<= 1) m2 = fmaxf(m2, __shfl_xor(m2, w));
    bal = __ballot(p2v == m2);
    int i2 = __ffs((int)((bal >> (g4 * 16)) & 0xFFFFu)) - 1;
    if (e == 0) {
        float inv2 = 1.f / (m1 + m2 + 1e-9f);
        int p0 = atomicAdd(&meta[i1], 1);
        tok[i1 * CAP + p0] = t; wgt[i1 * CAP + p0] = m1 * inv2;
        int p1 = atomicAdd(&meta[i2], 1);
        tok[i2 * CAP + p1] = t; wgt[i2 * CAP + p1] = m2 * inv2;
        tok[16 * CAP + t] = t; wgt[16 * CAP + t] = 1.f;
        inva[t] = make_int2(i1, p0);
        invb[t] = make_int2(i2, p1);
    }
}

// ---------------- W_up [E][H][2F] fp32 (+shared) -> wupT [17][2F][H] bf16, 64x64 tiles ----------------
__global__ __launch_bounds__(256) void k_tup(const float* __restrict__ Wup,
                                             const float* __restrict__ Wsup,
                                             ushort* __restrict__ dst) {
    __shared__ __align__(16) float tile[64][68];
    int bid = blockIdx.x;
    int e = bid >> 8, rem = bid & 255;
    int h0 = (rem >> 4) * 64, n0 = (rem & 15) * 64;
    const float* src = (e < 16) ? (Wup + (size_t)e * HD * 1024) : Wsup;
    int tid = threadIdx.x;
    int rr = tid >> 4, cc = (tid & 15) * 4;
#pragma unroll
    for (int q = 0; q < 4; ++q) {
        float4 v = *(const float4*)(src + (size_t)(h0 + q * 16 + rr) * 1024 + n0 + cc);
        *(float4*)(&tile[q * 16 + rr][cc]) = v;
    }
    __syncthreads();
#pragma unroll
    for (int q = 0; q < 4; ++q) {
        int nl = q * 16 + rr;
        ushort4 o;
        o.x = f2bf(tile[cc + 0][nl]);
        o.y = f2bf(tile[cc + 1][nl]);
        o.z = f2bf(tile[cc + 2][nl]);
        o.w = f2bf(tile[cc + 3][nl]);
        *(ushort4*)(dst + (size_t)e * 1048576 + (size_t)(n0 + nl) * 1024 + h0 + cc) = o;
    }
}

// ---------------- W_down [E][F][H] fp32 (+shared) -> wdT [17][H][F] bf16, 64x64 tiles ----------------
__global__ __launch_bounds__(256) void k_tdn(const float* __restrict__ Wdn,
                                             const float* __restrict__ Wsdn,
                                             ushort* __restrict__ dst) {
    __shared__ __align__(16) float tile[64][68];
    int bid = blockIdx.x;
    int e = bid >> 7, rem = bid & 127;
    int f0 = (rem >> 4) * 64, h0 = (rem & 15) * 64;
    const float* src = (e < 16) ? (Wdn + (size_t)e * FD * HD) : Wsdn;
    int tid = threadIdx.x;
    int rr = tid >> 4, cc = (tid & 15) * 4;
#pragma unroll
    for (int q = 0; q < 4; ++q) {
        float4 v = *(const float4*)(src + (size_t)(f0 + q * 16 + rr) * 1024 + h0 + cc);
        *(float4*)(&tile[q * 16 + rr][cc]) = v;
    }
    __syncthreads();
#pragma unroll
    for (int q = 0; q < 4; ++q) {
        int hl = q * 16 + rr;
        ushort4 o;
        o.x = f2bf(tile[cc + 0][hl]);
        o.y = f2bf(tile[cc + 1][hl]);
        o.z = f2bf(tile[cc + 2][hl]);
        o.w = f2bf(tile[cc + 3][hl]);
        *(ushort4*)(dst + (size_t)e * 524288 + (size_t)(h0 + hl) * 512 + f0 + cc) = o;
    }
}

// ---------------- finalize: build 256-row blocks, zero pad slots ----------------
__global__ void k_finalize(int* __restrict__ meta, int* __restrict__ tok,
                           float* __restrict__ wgt) {
    __shared__ int sN[NET], sPad[NET];
    int tid = threadIdx.x;
    if (tid == 0) {
        meta[16] = T_TOK;   // shared-expert count
        int idx = 0, yoff = 0;
        for (int e = 0; e < NET; e++) {
            int n = meta[e];
            int padded = (n + 255) & ~255;
            sN[e] = n; sPad[e] = padded;
            meta[416 + e] = yoff;
            for (int i = 0; i < padded; i += 256) {
                meta[32 + idx] = e; meta[160 + idx] = i; meta[288 + idx] = yoff + i; idx++;
            }
            yoff += n;
        }
        meta[17] = idx;
    }
    __syncthreads();
    for (int e = 0; e < NET; e++)
        for (int i = sN[e] + tid; i < sPad[e]; i += 256) {
            tok[e * CAP + i] = 0; wgt[e * CAP + i] = 0.f;
        }
}

// ---------------- grouped up-GEMM + SiLU ----------------
// BM=256, cols 128 gate + 128 up per block, BK=64, 512 thr (8 waves 4Mx2N),
// double-buffered LDS (2 x {A 32K | Bg 16K | Bu 16K}), depth-1 prefetch.
__global__ __launch_bounds__(512, 2) void k_up(const ushort* __restrict__ xb,
                                               const ushort* __restrict__ wupT,
                                               ushort* __restrict__ act,
                                               const int* __restrict__ tok,
                                               const int* __restrict__ meta) {
    __shared__ __align__(16) char smem[131072];
    int bid = blockIdx.x;
    int s = (bid & 7) * CPX + (bid >> 3);     // XCD swizzle: 4 cb of one rb per XCD
    int rb = s >> 2, cb = s & 3;
    if (rb >= meta[17]) return;
    int e = meta[32 + rb], rloc = meta[160 + rb], abrow = meta[288 + rb];
    int ne = meta[e];
    int tid = threadIdx.x, lane = tid & 63, wave = tid >> 6;

    int srow = tid >> 3;                       // 0..63 (row within 64-row issue)
    int col16 = (tid & 7) << 4;
    int swz = col16 ^ ((srow & 7) << 4);
    const int listBase = e * CAP + rloc;
    int tokr[4];
#pragma unroll
    for (int i = 0; i < 4; i++) tokr[i] = tok[listBase + i * 64 + srow];
    const char* xbase = (const char*)xb;
    const char* wb = (const char*)wupT + (size_t)e * 2097152;
    int ldsl = wave * 1024;                    // wave-uniform LDS slot within each 8KB issue

    int wr = wave >> 1, wc = wave & 1;
    int lr = lane & 15, lk = lane >> 4;
    int aOff = (wr * 64 + lr) * 128;
    int bOff = (wc * 64 + lr) * 128;
    int kp0 = (lk * 16) ^ ((lr & 7) << 4);
    int kp1 = (64 + lk * 16) ^ ((lr & 7) << 4);

    f32x4 accg[4][4], accu[4][4];
#pragma unroll
    for (int m = 0; m < 4; m++)
#pragma unroll
        for (int n = 0; n < 4; n++) {
            accg[m][n] = (f32x4){0.f, 0.f, 0.f, 0.f};
            accu[m][n] = (f32x4){0.f, 0.f, 0.f, 0.f};
        }

#define STAGE_UP(KT, D)                                                                   \
    {                                                                                     \
        char* base = smem + (D) * 65536;                                                  \
        int kB = (KT) * 128;                                                              \
        _Pragma("unroll")                                                                 \
        for (int i = 0; i < 4; i++)                                                       \
            gload16(xbase + (size_t)tokr[i] * 2048 + kB + swz, base + i * 8192 + ldsl);   \
        _Pragma("unroll")                                                                 \
        for (int i = 0; i < 2; i++)                                                       \
            gload16(wb + (size_t)(cb * 128 + i * 64 + srow) * 2048 + kB + swz,            \
                    base + 32768 + i * 8192 + ldsl);                                      \
        _Pragma("unroll")                                                                 \
        for (int i = 0; i < 2; i++)                                                       \
            gload16(wb + (size_t)(512 + cb * 128 + i * 64 + srow) * 2048 + kB + swz,      \
                    base + 49152 + i * 8192 + ldsl);                                      \
    }

    STAGE_UP(0, 0);
    asm volatile("s_waitcnt vmcnt(0)" ::: "memory");
    __syncthreads();
    int cur = 0;
#pragma unroll 1
    for (int kt = 0; kt < 16; ++kt) {
        if (kt < 15) STAGE_UP(kt + 1, cur ^ 1);
        const char* A  = smem + cur * 65536;
        const char* Bg = A + 32768;
        const char* Bu = A + 49152;
#pragma unroll
        for (int kk = 0; kk < 2; kk++) {
            int kp = kk ? kp1 : kp0;
            bf16x8 a[4], bg[4], bu[4];
#pragma unroll
            for (int m = 0; m < 4; m++) a[m] = *(const bf16x8*)(A + aOff + m * 2048 + kp);
#pragma unroll
            for (int n = 0; n < 4; n++) bg[n] = *(const bf16x8*)(Bg + bOff + n * 2048 + kp);
#pragma unroll
            for (int n = 0; n < 4; n++) bu[n] = *(const bf16x8*)(Bu + bOff + n * 2048 + kp);
#pragma unroll
            for (int m = 0; m < 4; m++)
#pragma unroll
                for (int n = 0; n < 4; n++) {
                    accg[m][n] = __builtin_amdgcn_mfma_f32_16x16x32_bf16(a[m], bg[n], accg[m][n], 0, 0, 0);
                    accu[m][n] = __builtin_amdgcn_mfma_f32_16x16x32_bf16(a[m], bu[n], accu[m][n], 0, 0, 0);
                }
        }
        asm volatile("s_waitcnt vmcnt(0)" ::: "memory");
        __syncthreads();
        cur ^= 1;
    }
    // SiLU(gate)*up -> bf16, stage in LDS [256][128]
    ushort* actl = (ushort*)smem;
#pragma unroll
    for (int m = 0; m < 4; m++)
#pragma unroll
        for (int n = 0; n < 4; n++)
#pragma unroll
            for (int j = 0; j < 4; j++) {
                float gv = accg[m][n][j];
                float uv = accu[m][n][j];
                float av = (gv / (1.f + __expf(-gv))) * uv;
                int row = wr * 64 + m * 16 + lk * 4 + j;
                int col = wc * 64 + n * 16 + lr;
                actl[row * 128 + col] = f2bf(av);
            }
    __syncthreads();
#pragma unroll
    for (int p = 0; p < 8; p++) {
        int c = p * 512 + tid;
        int row = c >> 4, off = (c & 15) << 4;
        if (rloc + row < ne)
            *(uint4*)((char*)act + (size_t)(abrow + row) * 1024 + cb * 256 + off) =
                *(const uint4*)((const char*)actl + row * 256 + off);
    }
#undef STAGE_UP
}

// ---------------- grouped down-GEMM + weighted bf16 store (compact) ----------------
// BM=256, BN=256, BK=64, K=512, 512 thr (8 waves 4Mx2N, 64x128 per wave),
// double-buffered LDS (2 x {A 32K | B 32K}), depth-1 prefetch.
__global__ __launch_bounds__(512, 2) void k_down(const ushort* __restrict__ act,
                                                 const ushort* __restrict__ wdT,
                                                 ushort* __restrict__ ybuf,
                                                 const float* __restrict__ wgt,
                                                 const int* __restrict__ meta) {
    __shared__ __align__(16) char smem[131072];
    int bid = blockIdx.x;
    int s = (bid & 7) * CPX + (bid >> 3);
    int rb = s >> 2, cb = s & 3;
    if (rb >= meta[17]) return;
    int e = meta[32 + rb], rloc = meta[160 + rb], abrow = meta[288 + rb];
    int ne = meta[e];
    int tid = threadIdx.x, lane = tid & 63, wave = tid >> 6;

    int srow = tid >> 3;
    int col16 = (tid & 7) << 4;
    int swz = col16 ^ ((srow & 7) << 4);
    const char* abase = (const char*)act + (size_t)abrow * 1024;
    const char* bbase = (const char*)wdT + (size_t)e * 1048576 + (size_t)cb * 256 * 1024;
    int ldsl = wave * 1024;

    int wr = wave >> 1, wc = wave & 1;
    int lr = lane & 15, lk = lane >> 4;
    int aOff = (wr * 64 + lr) * 128;
    int bOff = (wc * 128 + lr) * 128;
    int kp0 = (lk * 16) ^ ((lr & 7) << 4);
    int kp1 = (64 + lk * 16) ^ ((lr & 7) << 4);

    f32x4 acc[4][8];
#pragma unroll
    for (int m = 0; m < 4; m++)
#pragma unroll
        for (int n = 0; n < 8; n++) acc[m][n] = (f32x4){0.f, 0.f, 0.f, 0.f};

#define STAGE_DN(KT, D)                                                                  \
    {                                                                                    \
        char* base = smem + (D) * 65536;                                                 \
        int kB = (KT) * 128;                                                             \
        _Pragma("unroll")                                                                \
        for (int i = 0; i < 4; i++)                                                      \
            gload16(abase + (size_t)(i * 64 + srow) * 1024 + kB + swz,                   \
                    base + i * 8192 + ldsl);                                             \
        _Pragma("unroll")                                                                \
        for (int i = 0; i < 4; i++)                                                      \
            gload16(bbase + (size_t)(i * 64 + srow) * 1024 + kB + swz,                   \
                    base + 32768 + i * 8192 + ldsl);                                     \
    }

    STAGE_DN(0, 0);
    asm volatile("s_waitcnt vmcnt(0)" ::: "memory");
    __syncthreads();
    int cur = 0;
#pragma unroll 1
    for (int kt = 0; kt < 8; ++kt) {
        if (kt < 7) STAGE_DN(kt + 1, cur ^ 1);
        const char* A = smem + cur * 65536;
        const char* B = A + 32768;
#pragma unroll
        for (int kk = 0; kk < 2; kk++) {
            int kp = kk ? kp1 : kp0;
            bf16x8 a[4], b[8];
#pragma unroll
            for (int m = 0; m < 4; m++) a[m] = *(const bf16x8*)(A + aOff + m * 2048 + kp);
#pragma unroll
            for (int n = 0; n < 8; n++) b[n] = *(const bf16x8*)(B + bOff + n * 2048 + kp);
#pragma unroll
            for (int m = 0; m < 4; m++)
#pragma unroll
                for (int n = 0; n < 8; n++)
                    acc[m][n] = __builtin_amdgcn_mfma_f32_16x16x32_bf16(a[m], b[n], acc[m][n], 0, 0, 0);
        }
        asm volatile("s_waitcnt vmcnt(0)" ::: "memory");
        __syncthreads();
        cur ^= 1;
    }
    // scale by router weight, stage bf16 tile [256][256] in LDS (128KB)
    const int lb = e * CAP + rloc;
    ushort* yl = (ushort*)smem;
#pragma unroll
    for (int m = 0; m < 4; m++)
#pragma unroll
        for (int j = 0; j < 4; j++) {
            int row = wr * 64 + m * 16 + lk * 4 + j;
            float w = wgt[lb + row];
#pragma unroll
            for (int n = 0; n < 8; n++) {
                int col = wc * 128 + n * 16 + lr;
                yl[row * 256 + col] = f2bf(acc[m][n][j] * w);
            }
        }
    __syncthreads();
#pragma unroll
    for (int p = 0; p < 16; p++) {
        int c = p * 512 + tid;
        int row = c >> 5, off = (c & 31) << 4;
        if (rloc + row < ne)
            *(uint4*)((char*)ybuf + (size_t)(abrow + row) * 2048 + cb * 512 + off) =
                *(const uint4*)((const char*)yl + row * 512 + off);
    }
#undef STAGE_DN
}

// ---------------- per-token combine ----------------
__global__ __launch_bounds__(256) void k_combine(const ushort* __restrict__ y,
                                                 const int2* __restrict__ ia,
                                                 const int2* __restrict__ ib,
                                                 const int* __restrict__ meta,
                                                 float* __restrict__ out) {
    int t = blockIdx.x;
    int2 a = ia[t], b = ib[t];
    int r0 = (meta[416 + a.x] + a.y) << 10;
    int r1 = (meta[416 + b.x] + b.y) << 10;
    int rs = (meta[432] + t) << 10;
    int c = threadIdx.x << 2;
    ushort4 va = *(const ushort4*)(y + r0 + c);
    ushort4 vb = *(const ushort4*)(y + r1 + c);
    ushort4 vs = *(const ushort4*)(y + rs + c);
    float4 o;
    o.x = bf2f(va.x) + bf2f(vb.x) + bf2f(vs.x);
    o.y = bf2f(va.y) + bf2f(vb.y) + bf2f(vs.y);
    o.z = bf2f(va.z) + bf2f(vb.z) + bf2f(vs.z);
    o.w = bf2f(va.w) + bf2f(vb.w) + bf2f(vs.w);
    *(float4*)(out + ((size_t)t << 10) + c) = o;
}

extern "C" void kernel_launch(void* const* d_in, const int* in_sizes, int n_in,
                              void* d_out, int out_size, void* d_ws, size_t ws_size,
                              hipStream_t stream) {
    const float* x    = (const float*)d_in[0];
    const float* Wr   = (const float*)d_in[1];
    const float* Wup  = (const float*)d_in[2];
    const float* Wdn  = (const float*)d_in[3];
    const float* Wsup = (const float*)d_in[4];
    const float* Wsdn = (const float*)d_in[5];
    float* out = (float*)d_out;
    float* probs = out + (size_t)T_TOK * HD;

    if (ws_size < WS_NEEDED) return;

    char* ws = (char*)d_ws;
    ushort* xb    = (ushort*)(ws + OFF_XBF);
    ushort* wupT  = (ushort*)(ws + OFF_WUPT);
    ushort* wdT   = (ushort*)(ws + OFF_WDT);
    ushort* act   = (ushort*)(ws + OFF_ACT);
    int2*   inva  = (int2*)(ws + OFF_EIDX);
    int2*   invb  = (int2*)(ws + OFF_EW);
    int*    tok   = (int*)(ws + OFF_TOK);
    float*  wgt   = (float*)(ws + OFF_WGT);
    int*    meta  = (int*)(ws + OFF_META);
    ushort* ybuf  = (ushort*)(ws + OFF_XBF);   // aliases xb+wupT (dead after k_up)

    hipMemsetAsync(meta, 0, 4096, stream);

    k_tup<<<NET * 256, 256, 0, stream>>>(Wup, Wsup, wupT);
    k_tdn<<<NET * 128, 256, 0, stream>>>(Wdn, Wsdn, wdT);
    k_router<<<T_TOK / 16, 256, 0, stream>>>(x, Wr, probs, inva, invb, xb, tok, wgt, meta);
    k_finalize<<<1, 256, 0, stream>>>(meta, tok, wgt);
    k_up<<<MAXWG, 512, 0, stream>>>(xb, wupT, act, tok, meta);
    k_down<<<MAXWG, 512, 0, stream>>>(act, wdT, ybuf, wgt, meta);
    k_combine<<<T_TOK, 256, 0, stream>>>(ybuf, inva, invb, meta, out);
}